// Round 8
// baseline (332.779 us; speedup 1.0000x reference)
//
#include <hip/hip_runtime.h>
#include <math.h>
#include <float.h>

typedef __attribute__((ext_vector_type(8))) short short8;
typedef __attribute__((ext_vector_type(8))) ushort ushort8;
typedef __attribute__((ext_vector_type(4))) float f32x4;

namespace {

constexpr int B = 256;
constexpr int M = 65536;
constexpr int D = 1024;
constexpr float DECAY_EPS = 1e-8f;
constexpr float DECAY_RATE = 0.999f;

constexpr int BN = 64;          // keys per GEMM block
constexpr int BK = 32;          // k per step
constexpr int KSTEPS = D / BK;  // 32

constexpr int CHUNKS = 8;           // top-k chunks per row
constexpr int CHUNK = M / CHUNKS;   // 8192
constexpr int NCAND = CHUNKS * 8;   // 64 candidates per row

__device__ inline ushort f2bf(float f) {
  union { float f; unsigned u; } v; v.f = f;
  unsigned r = v.u + 0x7fffu + ((v.u >> 16) & 1u);  // RNE
  return (ushort)(r >> 16);
}

__device__ inline short8 pack8(float4 u, float4 v) {
  short8 r;
  r[0] = (short)f2bf(u.x); r[1] = (short)f2bf(u.y);
  r[2] = (short)f2bf(u.z); r[3] = (short)f2bf(u.w);
  r[4] = (short)f2bf(v.x); r[5] = (short)f2bf(v.y);
  r[6] = (short)f2bf(v.z); r[7] = (short)f2bf(v.w);
  return r;
}

__device__ inline float dot4(float4 a) {
  return a.x * a.x + a.y * a.y + a.z * a.z + a.w * a.w;
}

// ---------------------------------------------------------------------------
// Kernel 1: normalize queries, emit bf16 in MFMA A-fragment order:
// qnf[(kt*16 + mt)*512 + l*8 + j] = qn[mt*16 + (l&15)][kt*32 + (l>>4)*8 + j]
// ---------------------------------------------------------------------------
__global__ void prep_q_kernel(const float* __restrict__ q, ushort* __restrict__ qnf) {
  const int r = blockIdx.x;
  const int t = threadIdx.x;  // 256 threads x float4
  float4 v = reinterpret_cast<const float4*>(q + (size_t)r * D)[t];
  float ss = dot4(v);
#pragma unroll
  for (int off = 32; off; off >>= 1) ss += __shfl_down(ss, off, 64);
  __shared__ float red[4];
  if ((t & 63) == 0) red[t >> 6] = ss;
  __syncthreads();
  const float inv = 1.0f / fmaxf(sqrtf(red[0] + red[1] + red[2] + red[3]), DECAY_EPS);
  ushort4 o;
  o.x = f2bf(v.x * inv); o.y = f2bf(v.y * inv);
  o.z = f2bf(v.z * inv); o.w = f2bf(v.w * inv);
  const int k0 = t * 4;
  const int kt = k0 >> 5;
  const int lane_slot = (r & 15) + 16 * ((k0 & 31) >> 3);
  const int j0 = k0 & 7;  // 0 or 4
  *reinterpret_cast<ushort4*>(qnf + (size_t)(kt * 16 + (r >> 4)) * 512 + lane_slot * 8 + j0) = o;
}

// ---------------------------------------------------------------------------
// Kernel 2: bf16-MFMA scores -> bf16 score matrix [B][M].
// r2 structure (BN=64, BK=32, 256 thr / 4 waves, acc[4][4], conflict-free
// XOR-swizzled bf16 LDS for keys) + T4 counted waits: raw s_barrier with
// lgkmcnt(0) only, so register-dest key loads (issued 3 steps ahead,
// nvA/nvB ping-pong) are NEVER drained at barriers. A-loads issued first
// each iter so the MFMA wait is vmcnt(2).
// ---------------------------------------------------------------------------
__global__ __launch_bounds__(256, 4) void score_gemm_kernel(
    const ushort* __restrict__ qnf, const float* __restrict__ keys,
    const float* __restrict__ importance, const int* __restrict__ atimes,
    const int* __restrict__ acnts, const int* __restrict__ ctime,
    ushort* __restrict__ scores) {
  __shared__ alignas(16) ushort Bs[2][BN * BK];  // 2 x 4 KB
  __shared__ float cscale[BN];

  const int t = threadIdx.x;
  const int lane = t & 63;
  const int w = t >> 6;      // wave 0..3
  const int h = lane >> 4;   // 0..3
  const int q = lane & 15;   // 0..15
  const int jb = blockIdx.x * BN;

  // staging: thread t -> key row rw (0..63), 8-float chunk cw (0..3)
  const int rw = t >> 2;
  const int cw = t & 3;
  const float* kptr = keys + (size_t)(jb + rw) * D + cw * 8;
  const int wo = rw * BK + ((cw ^ ((rw >> 1) & 3)) * 8);

  // frag read offsets: row = nf*16+q, slot h ^ ((row>>1)&3)
  int roff[4];
#pragma unroll
  for (int nf = 0; nf < 4; ++nf) {
    const int row = nf * 16 + q;
    roff[nf] = row * BK + ((h ^ ((row >> 1) & 3)) * 8);
  }

  f32x4 acc[4][4];
#pragma unroll
  for (int f = 0; f < 4; ++f)
#pragma unroll
    for (int n = 0; n < 4; ++n) acc[f][n] = (f32x4)(0.0f);

  float kn2 = 0.0f;

  // prologue: stage step 0 synchronously; issue loads for steps 1 and 2
  {
    float4 v0 = *reinterpret_cast<const float4*>(kptr);
    float4 v1 = *reinterpret_cast<const float4*>(kptr + 4);
    kn2 += dot4(v0) + dot4(v1);
    *reinterpret_cast<short8*>(&Bs[0][wo]) = pack8(v0, v1);
  }
  float4 nvA0 = *reinterpret_cast<const float4*>(kptr + 1 * BK);
  float4 nvA1 = *reinterpret_cast<const float4*>(kptr + 1 * BK + 4);
  float4 nvB0 = *reinterpret_cast<const float4*>(kptr + 2 * BK);
  float4 nvB1 = *reinterpret_cast<const float4*>(kptr + 2 * BK + 4);
  asm volatile("s_waitcnt lgkmcnt(0)" ::: "memory");
  __builtin_amdgcn_s_barrier();

  const short8* ap = reinterpret_cast<const short8*>(qnf) + (size_t)(w * 4) * 64 + lane;

#pragma unroll
  for (int s = 0; s < KSTEPS; ++s) {
    const int cur = s & 1;
    // 1. A-frag loads for step s (L2-resident qnf) -- issued OLDEST
    short8 a0 = ap[(size_t)(s * 16 + 0) * 64];
    short8 a1 = ap[(size_t)(s * 16 + 1) * 64];
    short8 a2 = ap[(size_t)(s * 16 + 2) * 64];
    short8 a3 = ap[(size_t)(s * 16 + 3) * 64];
    // 2. convert + stage step s+1 (data loaded 2 steps ago), accumulate norm
    if (s < KSTEPS - 1) {
      float4 u0 = (s & 1) ? nvB0 : nvA0;
      float4 u1 = (s & 1) ? nvB1 : nvA1;
      kn2 += dot4(u0) + dot4(u1);
      *reinterpret_cast<short8*>(&Bs[cur ^ 1][wo]) = pack8(u0, u1);
    }
    // 3. issue key loads for step s+3 into the freed register set
    if (s < KSTEPS - 3) {
      if (s & 1) {
        nvB0 = *reinterpret_cast<const float4*>(kptr + (s + 3) * BK);
        nvB1 = *reinterpret_cast<const float4*>(kptr + (s + 3) * BK + 4);
      } else {
        nvA0 = *reinterpret_cast<const float4*>(kptr + (s + 3) * BK);
        nvA1 = *reinterpret_cast<const float4*>(kptr + (s + 3) * BK + 4);
      }
    }
    // 4. B-frag reads from LDS
    short8 b0 = *reinterpret_cast<const short8*>(&Bs[cur][roff[0]]);
    short8 b1 = *reinterpret_cast<const short8*>(&Bs[cur][roff[1]]);
    short8 b2 = *reinterpret_cast<const short8*>(&Bs[cur][roff[2]]);
    short8 b3 = *reinterpret_cast<const short8*>(&Bs[cur][roff[3]]);
    // 5. MFMA (A-wait is vmcnt(2): only the 2 key loads are newer)
#pragma unroll
    for (int f = 0; f < 4; ++f) {
      const short8 af = (f == 0) ? a0 : (f == 1) ? a1 : (f == 2) ? a2 : a3;
      acc[f][0] = __builtin_amdgcn_mfma_f32_16x16x32_bf16(af, b0, acc[f][0], 0, 0, 0);
      acc[f][1] = __builtin_amdgcn_mfma_f32_16x16x32_bf16(af, b1, acc[f][1], 0, 0, 0);
      acc[f][2] = __builtin_amdgcn_mfma_f32_16x16x32_bf16(af, b2, acc[f][2], 0, 0, 0);
      acc[f][3] = __builtin_amdgcn_mfma_f32_16x16x32_bf16(af, b3, acc[f][3], 0, 0, 0);
    }
    // 6. barrier WITHOUT vmcnt drain: only LDS ops must settle
    if (s < KSTEPS - 1) {
      asm volatile("s_waitcnt lgkmcnt(0)" ::: "memory");
      __builtin_amdgcn_s_barrier();
    }
  }

  // key norms: the 4 staging threads of row rw are consecutive lanes
  kn2 += __shfl_xor(kn2, 1, 64);
  kn2 += __shfl_xor(kn2, 2, 64);
  if (cw == 0) {
    const int j = jb + rw;
    const float dt = (float)(ctime[0] - atimes[j]);
    const float mult = powf(DECAY_RATE, dt) * importance[j] * log1pf((float)acnts[j]);
    cscale[rw] = mult / fmaxf(sqrtf(kn2), DECAY_EPS);
  }
  __syncthreads();

  // epilogue: C/D col = nf*16+q, row = (w*4+f)*16 + h*4 + rr; bf16 packed
  float cs[4];
#pragma unroll
  for (int nf = 0; nf < 4; ++nf) cs[nf] = cscale[nf * 16 + q];
#pragma unroll
  for (int f = 0; f < 4; ++f) {
    const int row0 = (w * 4 + f) * 16 + (h << 2);
#pragma unroll
    for (int nf = 0; nf < 4; ++nf) {
#pragma unroll
      for (int rr = 0; rr < 4; ++rr) {
        const float v = acc[f][nf][rr] * cs[nf];
        const float vn = __shfl_xor(v, 1, 64);
        if (!(q & 1)) {
          const uint pk = (uint)f2bf(v) | ((uint)f2bf(vn) << 16);
          *reinterpret_cast<uint*>(
              scores + (size_t)(row0 + rr) * M + jb + nf * 16 + q) = pk;
        }
      }
    }
  }
}

// ---------------------------------------------------------------------------
// Kernel 3 (stage A): per (row, chunk) top-8 indices over bf16 scores.
// Packed u32 = (monotone_key16 << 16) | global_idx16; integer compares.
// ---------------------------------------------------------------------------
__global__ __launch_bounds__(256) void topk_partial_kernel(
    const ushort* __restrict__ scores, int* __restrict__ cand_i) {
  const int b = blockIdx.y;
  const int c = blockIdx.x;
  const int t = threadIdx.x;
  const int lane = t & 63, w = t >> 6;
  const ushort8* base8 =
      reinterpret_cast<const ushort8*>(scores + (size_t)b * M + (size_t)c * CHUNK);

  uint s8[8];
#pragma unroll
  for (int i = 0; i < 8; ++i) s8[i] = 0;

  auto ins = [&](uint x) {
    if (x > s8[0]) {
#pragma unroll
      for (int i = 0; i < 8; ++i) {
        const bool up = (i < 7) && (x > s8[i + 1]);
        const uint keep = (x > s8[i]) ? x : s8[i];
        s8[i] = up ? s8[i + 1] : keep;
      }
    }
  };

  const uint jbase = (uint)c * CHUNK;
#pragma unroll
  for (int it = 0; it < CHUNK / (256 * 8); ++it) {  // 4 iters
    const int slot = it * 256 + t;
    const ushort8 v = base8[slot];
    const uint j0 = jbase + (uint)slot * 8;
#pragma unroll
    for (int e = 0; e < 8; ++e) {
      const ushort s = (ushort)v[e];
      const ushort key = (s & 0x8000) ? (ushort)~s : (ushort)(s | 0x8000);
      ins(((uint)key << 16) | ((j0 + e) & 0xFFFFu));
    }
  }

  __shared__ uint ls[2048];
#pragma unroll
  for (int i = 0; i < 8; ++i) ls[t * 8 + i] = s8[i];
  __syncthreads();

  __shared__ uint rs4[4];
  __shared__ int rp4[4];
  for (int r = 0; r < 8; ++r) {
    uint ms = 0;
    int mp = 0;
#pragma unroll
    for (int i = 0; i < 8; ++i) {
      const uint v = ls[i * 256 + t];
      if (v > ms) { ms = v; mp = i * 256 + t; }
    }
#pragma unroll
    for (int off = 32; off; off >>= 1) {
      const uint ov = __shfl_xor(ms, off, 64);
      const int op = __shfl_xor(mp, off, 64);
      if (ov > ms) { ms = ov; mp = op; }
    }
    if (lane == 0) { rs4[w] = ms; rp4[w] = mp; }
    __syncthreads();
    if (t == 0) {
      uint bs = 0;
      int bp = 0;
#pragma unroll
      for (int i = 0; i < 4; ++i)
        if (rs4[i] > bs) { bs = rs4[i]; bp = rp4[i]; }
      cand_i[((size_t)b * CHUNKS + c) * 8 + r] = (int)(ls[bp] & 0xFFFFu);
      ls[bp] = 0;
    }
    __syncthreads();
  }
}

// ---------------------------------------------------------------------------
// Kernel 4 (stage B): exact fp32 rescore of 64 candidates, top-8, softmax,
// weighted value gather. One block (512 thr = 8 waves) per row.
// ---------------------------------------------------------------------------
__global__ __launch_bounds__(512) void rescore_kernel(
    const int* __restrict__ cand_i, const float* __restrict__ query,
    const float* __restrict__ keys, const float* __restrict__ values,
    const float* __restrict__ importance, const int* __restrict__ atimes,
    const int* __restrict__ acnts, const int* __restrict__ ctime,
    float* __restrict__ outc, float* __restrict__ conf) {
  const int b = blockIdx.x;
  const int t = threadIdx.x;
  const int lane = t & 63, w = t >> 6;

  const float4* qv4 = reinterpret_cast<const float4*>(query + (size_t)b * D + lane * 16);
  float4 q0 = qv4[0], q1 = qv4[1], q2 = qv4[2], q3 = qv4[3];
  float ssq = dot4(q0) + dot4(q1) + dot4(q2) + dot4(q3);
#pragma unroll
  for (int off = 32; off; off >>= 1) ssq += __shfl_xor(ssq, off, 64);
  const float qdn = fmaxf(sqrtf(ssq), DECAY_EPS);
  const int ct = ctime[0];

  __shared__ float sc[NCAND];
  __shared__ int sidx[NCAND];

  for (int u = 0; u < 8; ++u) {
    const int c = w * 8 + u;
    const int j = cand_i[(size_t)b * NCAND + c];
    const float4* kv4 = reinterpret_cast<const float4*>(keys + (size_t)j * D + lane * 16);
    const float4 k0 = kv4[0], k1 = kv4[1], k2 = kv4[2], k3 = kv4[3];
    float dd = q0.x * k0.x + q0.y * k0.y + q0.z * k0.z + q0.w * k0.w
             + q1.x * k1.x + q1.y * k1.y + q1.z * k1.z + q1.w * k1.w
             + q2.x * k2.x + q2.y * k2.y + q2.z * k2.z + q2.w * k2.w
             + q3.x * k3.x + q3.y * k3.y + q3.z * k3.z + q3.w * k3.w;
    float nn = dot4(k0) + dot4(k1) + dot4(k2) + dot4(k3);
#pragma unroll
    for (int off = 32; off; off >>= 1) {
      dd += __shfl_xor(dd, off, 64);
      nn += __shfl_xor(nn, off, 64);
    }
    if (lane == 0) {
      const float dtv = (float)(ct - atimes[j]);
      const float mult = powf(DECAY_RATE, dtv) * importance[j] * log1pf((float)acnts[j]);
      sc[c] = dd / (qdn * fmaxf(sqrtf(nn), DECAY_EPS)) * mult;
      sidx[c] = j;
    }
  }
  __syncthreads();

  __shared__ float w8s[8];
  __shared__ int g8[8];
  __shared__ float confv;
  __shared__ float tls[8];
  __shared__ int tli[8];
  if (w == 0) {
    float myv = sc[lane];
    for (int r = 0; r < 8; ++r) {
      float m = myv;
      int mi = lane;
#pragma unroll
      for (int off = 32; off; off >>= 1) {
        const float ov = __shfl_xor(m, off, 64);
        const int oi = __shfl_xor(mi, off, 64);
        if (ov > m || (ov == m && oi < mi)) { m = ov; mi = oi; }
      }
      if (lane == 0) { tls[r] = m; tli[r] = mi; }
      if (lane == mi) myv = -FLT_MAX;
    }
    if (lane == 0) {
      const float mx = tls[0];
      float e[8];
      float z = 0.0f;
#pragma unroll
      for (int r = 0; r < 8; ++r) { e[r] = expf(tls[r] - mx); z += e[r]; }
      const float invz = 1.0f / z;
#pragma unroll
      for (int r = 0; r < 8; ++r) { w8s[r] = e[r] * invz; g8[r] = sidx[tli[r]]; }
      confv = w8s[0];
    }
  }
  __syncthreads();

  float2 acc = make_float2(0.0f, 0.0f);
#pragma unroll
  for (int k = 0; k < 8; ++k) {
    const float wk = w8s[k];
    const float2 v = *reinterpret_cast<const float2*>(values + (size_t)g8[k] * D + 2 * t);
    acc.x = fmaf(wk, v.x, acc.x);
    acc.y = fmaf(wk, v.y, acc.y);
  }
  *reinterpret_cast<float2*>(outc + (size_t)b * D + 2 * t) = acc;
  if (t == 0) conf[b] = confv;
}

}  // namespace

extern "C" void kernel_launch(void* const* d_in, const int* in_sizes, int n_in,
                              void* d_out, int out_size, void* d_ws, size_t ws_size,
                              hipStream_t stream) {
  const float* query = (const float*)d_in[0];
  const float* keys = (const float*)d_in[1];
  const float* values = (const float*)d_in[2];
  const float* importance = (const float*)d_in[3];
  const int* atimes = (const int*)d_in[4];
  const int* acnts = (const int*)d_in[5];
  const int* ctime = (const int*)d_in[6];

  float* out = (float*)d_out;  // combined [B*D] then confidence [B]
  ushort* qnf = (ushort*)d_ws;                 // 512 KB
  ushort* scores = qnf + (size_t)B * D;        // 32 MB bf16
  int* cand = (int*)(scores + (size_t)B * M);  // 64 KB

  prep_q_kernel<<<B, 256, 0, stream>>>(query, qnf);
  score_gemm_kernel<<<M / BN, 256, 0, stream>>>(qnf, keys, importance, atimes,
                                                acnts, ctime, scores);
  dim3 gA(CHUNKS, B);
  topk_partial_kernel<<<gA, 256, 0, stream>>>(scores, cand);
  rescore_kernel<<<B, 512, 0, stream>>>(cand, query, keys, values, importance,
                                        atimes, acnts, ctime, out, out + (size_t)B * D);
}

// Round 9
// 156.067 us; speedup vs baseline: 2.1323x; 2.1323x over previous
//
#include <hip/hip_runtime.h>
#include <math.h>
#include <float.h>

typedef __attribute__((ext_vector_type(8))) short short8;
typedef __attribute__((ext_vector_type(8))) ushort ushort8;
typedef __attribute__((ext_vector_type(4))) float f32x4;

namespace {

constexpr int B = 256;
constexpr int M = 65536;
constexpr int D = 1024;
constexpr float DECAY_EPS = 1e-8f;
constexpr float DECAY_RATE = 0.999f;

constexpr int BN = 64;          // keys per GEMM block
constexpr int BK = 32;          // k per step
constexpr int KSTEPS = D / BK;  // 32

constexpr int CHUNKS = 8;           // top-k chunks per row
constexpr int CHUNK = M / CHUNKS;   // 8192
constexpr int NCAND = CHUNKS * 8;   // 64 candidates per row

__device__ inline ushort f2bf(float f) {
  union { float f; unsigned u; } v; v.f = f;
  unsigned r = v.u + 0x7fffu + ((v.u >> 16) & 1u);  // RNE
  return (ushort)(r >> 16);
}

__device__ inline float dot4(float4 a) {
  return a.x * a.x + a.y * a.y + a.z * a.z + a.w * a.w;
}

// ---------------------------------------------------------------------------
// Kernel 1: normalize queries, emit bf16 in MFMA A-fragment order:
// qnf[(kt*16 + mt)*512 + l*8 + j] = qn[mt*16 + (l&15)][kt*32 + (l>>4)*8 + j]
// ---------------------------------------------------------------------------
__global__ void prep_q_kernel(const float* __restrict__ q, ushort* __restrict__ qnf) {
  const int r = blockIdx.x;
  const int t = threadIdx.x;  // 256 threads x float4
  float4 v = reinterpret_cast<const float4*>(q + (size_t)r * D)[t];
  float ss = dot4(v);
#pragma unroll
  for (int off = 32; off; off >>= 1) ss += __shfl_down(ss, off, 64);
  __shared__ float red[4];
  if ((t & 63) == 0) red[t >> 6] = ss;
  __syncthreads();
  const float inv = 1.0f / fmaxf(sqrtf(red[0] + red[1] + red[2] + red[3]), DECAY_EPS);
  ushort4 o;
  o.x = f2bf(v.x * inv); o.y = f2bf(v.y * inv);
  o.z = f2bf(v.z * inv); o.w = f2bf(v.w * inv);
  const int k0 = t * 4;
  const int kt = k0 >> 5;
  const int lane_slot = (r & 15) + 16 * ((k0 & 31) >> 3);
  const int j0 = k0 & 7;  // 0 or 4
  *reinterpret_cast<ushort4*>(qnf + (size_t)(kt * 16 + (r >> 4)) * 512 + lane_slot * 8 + j0) = o;
}

// ---------------------------------------------------------------------------
// Kernel 2: bf16-MFMA scores -> bf16 score matrix [B][M].
// ROUND-2 STRUCTURE VERBATIM (best measured GEMM, ~90us): BN=64, BK=32,
// 256 thr / 4 waves, acc[4][4], keys reg-staged -> XOR-swizzled bf16 LDS,
// next-step loads issued before compute, plain __syncthreads per step.
// Only delta: epilogue stores packed bf16 scores (32 MB instead of 64).
// ---------------------------------------------------------------------------
__global__ __launch_bounds__(256) void score_gemm_kernel(
    const ushort* __restrict__ qnf, const float* __restrict__ keys,
    const float* __restrict__ importance, const int* __restrict__ atimes,
    const int* __restrict__ acnts, const int* __restrict__ ctime,
    ushort* __restrict__ scores) {
  __shared__ alignas(16) ushort Bs[2][BN * BK];
  __shared__ float cscale[BN];

  const int t = threadIdx.x;
  const int lane = t & 63;
  const int w = t >> 6;
  const int jb = blockIdx.x * BN;

  // staging: thread t stages key row rw, k-chunk cw (8 floats)
  const int rw = t >> 2;
  const int cw = t & 3;
  const float* kptr = keys + (size_t)(jb + rw) * D + cw * 8;
  // swizzled LDS elem offset: slot = cw ^ ((rw>>1)&3), 8 bf16 per slot
  const int woff = rw * BK + ((cw ^ ((rw >> 1) & 3)) * 8);

  f32x4 acc[4][4];
#pragma unroll
  for (int f = 0; f < 4; ++f)
#pragma unroll
    for (int n = 0; n < 4; ++n) acc[f][n] = (f32x4)(0.0f);

  float kn2 = 0.0f;

  // prologue: stage step 0
  {
    float4 v0 = *reinterpret_cast<const float4*>(kptr);
    float4 v1 = *reinterpret_cast<const float4*>(kptr + 4);
    kn2 += dot4(v0) + dot4(v1);
    short8 pk;
    pk[0] = (short)f2bf(v0.x); pk[1] = (short)f2bf(v0.y);
    pk[2] = (short)f2bf(v0.z); pk[3] = (short)f2bf(v0.w);
    pk[4] = (short)f2bf(v1.x); pk[5] = (short)f2bf(v1.y);
    pk[6] = (short)f2bf(v1.z); pk[7] = (short)f2bf(v1.w);
    *reinterpret_cast<short8*>(&Bs[0][woff]) = pk;
  }
  __syncthreads();

  // B-frag read offsets (swizzle matches write): lane reads row nf*16+(lane&15),
  // k-slot (lane>>4) ^ ((row>>1)&3)
  int roff[4];
#pragma unroll
  for (int nf = 0; nf < 4; ++nf) {
    const int row = nf * 16 + (lane & 15);
    roff[nf] = row * BK + (((lane >> 4) ^ ((row >> 1) & 3)) * 8);
  }

  for (int kt = 0; kt < KSTEPS; ++kt) {
    const int cur = kt & 1;
    float4 nv0, nv1;
    if (kt + 1 < KSTEPS) {
      nv0 = *reinterpret_cast<const float4*>(kptr + (kt + 1) * BK);
      nv1 = *reinterpret_cast<const float4*>(kptr + (kt + 1) * BK + 4);
    }
    // A fragments: coalesced 16B/lane from qnf (L2)
    short8 a[4];
    const short8* ap = reinterpret_cast<const short8*>(qnf) + (size_t)(kt * 16 + w * 4) * 64 + lane;
#pragma unroll
    for (int f = 0; f < 4; ++f) a[f] = ap[f * 64];
    // B fragments from LDS
    short8 bb[4];
#pragma unroll
    for (int nf = 0; nf < 4; ++nf)
      bb[nf] = *reinterpret_cast<const short8*>(&Bs[cur][roff[nf]]);
#pragma unroll
    for (int f = 0; f < 4; ++f)
#pragma unroll
      for (int nf = 0; nf < 4; ++nf)
        acc[f][nf] = __builtin_amdgcn_mfma_f32_16x16x32_bf16(a[f], bb[nf], acc[f][nf], 0, 0, 0);
    if (kt + 1 < KSTEPS) {
      kn2 += dot4(nv0) + dot4(nv1);
      short8 pk;
      pk[0] = (short)f2bf(nv0.x); pk[1] = (short)f2bf(nv0.y);
      pk[2] = (short)f2bf(nv0.z); pk[3] = (short)f2bf(nv0.w);
      pk[4] = (short)f2bf(nv1.x); pk[5] = (short)f2bf(nv1.y);
      pk[6] = (short)f2bf(nv1.z); pk[7] = (short)f2bf(nv1.w);
      *reinterpret_cast<short8*>(&Bs[cur ^ 1][woff]) = pk;
    }
    __syncthreads();
  }

  // key norm^2: reduce over the 4 staging threads of row rw (consecutive lanes)
  kn2 += __shfl_xor(kn2, 1, 64);
  kn2 += __shfl_xor(kn2, 2, 64);
  if (cw == 0) {
    const int j = jb + rw;
    const float dt = (float)(ctime[0] - atimes[j]);
    const float mult = powf(DECAY_RATE, dt) * importance[j] * log1pf((float)acnts[j]);
    cscale[rw] = mult / fmaxf(sqrtf(kn2), DECAY_EPS);
  }
  __syncthreads();

  // epilogue: C/D layout col=lane&15, row=(lane>>4)*4+reg; packed bf16 stores
  const int q = lane & 15;
  float cs[4];
#pragma unroll
  for (int nf = 0; nf < 4; ++nf) cs[nf] = cscale[nf * 16 + q];
#pragma unroll
  for (int f = 0; f < 4; ++f) {
    const int row0 = (w * 4 + f) * 16 + ((lane >> 4) << 2);
#pragma unroll
    for (int nf = 0; nf < 4; ++nf) {
#pragma unroll
      for (int rr = 0; rr < 4; ++rr) {
        const float v = acc[f][nf][rr] * cs[nf];
        const float vn = __shfl_xor(v, 1, 64);
        if (!(q & 1)) {
          const uint pk = (uint)f2bf(v) | ((uint)f2bf(vn) << 16);
          *reinterpret_cast<uint*>(
              scores + (size_t)(row0 + rr) * M + jb + nf * 16 + q) = pk;
        }
      }
    }
  }
}

// ---------------------------------------------------------------------------
// Kernel 3 (stage A): per (row, chunk) top-8 indices over bf16 scores.
// Packed u32 = (monotone_key16 << 16) | global_idx16; integer compares.
// ---------------------------------------------------------------------------
__global__ __launch_bounds__(256) void topk_partial_kernel(
    const ushort* __restrict__ scores, int* __restrict__ cand_i) {
  const int b = blockIdx.y;
  const int c = blockIdx.x;
  const int t = threadIdx.x;
  const int lane = t & 63, w = t >> 6;
  const ushort8* base8 =
      reinterpret_cast<const ushort8*>(scores + (size_t)b * M + (size_t)c * CHUNK);

  uint s8[8];
#pragma unroll
  for (int i = 0; i < 8; ++i) s8[i] = 0;

  auto ins = [&](uint x) {
    if (x > s8[0]) {
#pragma unroll
      for (int i = 0; i < 8; ++i) {
        const bool up = (i < 7) && (x > s8[i + 1]);
        const uint keep = (x > s8[i]) ? x : s8[i];
        s8[i] = up ? s8[i + 1] : keep;
      }
    }
  };

  const uint jbase = (uint)c * CHUNK;
#pragma unroll
  for (int it = 0; it < CHUNK / (256 * 8); ++it) {  // 4 iters
    const int slot = it * 256 + t;
    const ushort8 v = base8[slot];
    const uint j0 = jbase + (uint)slot * 8;
#pragma unroll
    for (int e = 0; e < 8; ++e) {
      const ushort s = (ushort)v[e];
      const ushort key = (s & 0x8000) ? (ushort)~s : (ushort)(s | 0x8000);
      ins(((uint)key << 16) | ((j0 + e) & 0xFFFFu));
    }
  }

  __shared__ uint ls[2048];
#pragma unroll
  for (int i = 0; i < 8; ++i) ls[t * 8 + i] = s8[i];
  __syncthreads();

  __shared__ uint rs4[4];
  __shared__ int rp4[4];
  for (int r = 0; r < 8; ++r) {
    uint ms = 0;
    int mp = 0;
#pragma unroll
    for (int i = 0; i < 8; ++i) {
      const uint v = ls[i * 256 + t];
      if (v > ms) { ms = v; mp = i * 256 + t; }
    }
#pragma unroll
    for (int off = 32; off; off >>= 1) {
      const uint ov = __shfl_xor(ms, off, 64);
      const int op = __shfl_xor(mp, off, 64);
      if (ov > ms) { ms = ov; mp = op; }
    }
    if (lane == 0) { rs4[w] = ms; rp4[w] = mp; }
    __syncthreads();
    if (t == 0) {
      uint bs = 0;
      int bp = 0;
#pragma unroll
      for (int i = 0; i < 4; ++i)
        if (rs4[i] > bs) { bs = rs4[i]; bp = rp4[i]; }
      cand_i[((size_t)b * CHUNKS + c) * 8 + r] = (int)(ls[bp] & 0xFFFFu);
      ls[bp] = 0;
    }
    __syncthreads();
  }
}

// ---------------------------------------------------------------------------
// Kernel 4 (stage B): exact fp32 rescore of 64 candidates, top-8, softmax,
// weighted value gather. One block (512 thr = 8 waves) per row.
// ---------------------------------------------------------------------------
__global__ __launch_bounds__(512) void rescore_kernel(
    const int* __restrict__ cand_i, const float* __restrict__ query,
    const float* __restrict__ keys, const float* __restrict__ values,
    const float* __restrict__ importance, const int* __restrict__ atimes,
    const int* __restrict__ acnts, const int* __restrict__ ctime,
    float* __restrict__ outc, float* __restrict__ conf) {
  const int b = blockIdx.x;
  const int t = threadIdx.x;
  const int lane = t & 63, w = t >> 6;

  const float4* qv4 = reinterpret_cast<const float4*>(query + (size_t)b * D + lane * 16);
  float4 q0 = qv4[0], q1 = qv4[1], q2 = qv4[2], q3 = qv4[3];
  float ssq = dot4(q0) + dot4(q1) + dot4(q2) + dot4(q3);
#pragma unroll
  for (int off = 32; off; off >>= 1) ssq += __shfl_xor(ssq, off, 64);
  const float qdn = fmaxf(sqrtf(ssq), DECAY_EPS);
  const int ct = ctime[0];

  __shared__ float sc[NCAND];
  __shared__ int sidx[NCAND];

  for (int u = 0; u < 8; ++u) {
    const int c = w * 8 + u;
    const int j = cand_i[(size_t)b * NCAND + c];
    const float4* kv4 = reinterpret_cast<const float4*>(keys + (size_t)j * D + lane * 16);
    const float4 k0 = kv4[0], k1 = kv4[1], k2 = kv4[2], k3 = kv4[3];
    float dd = q0.x * k0.x + q0.y * k0.y + q0.z * k0.z + q0.w * k0.w
             + q1.x * k1.x + q1.y * k1.y + q1.z * k1.z + q1.w * k1.w
             + q2.x * k2.x + q2.y * k2.y + q2.z * k2.z + q2.w * k2.w
             + q3.x * k3.x + q3.y * k3.y + q3.z * k3.z + q3.w * k3.w;
    float nn = dot4(k0) + dot4(k1) + dot4(k2) + dot4(k3);
#pragma unroll
    for (int off = 32; off; off >>= 1) {
      dd += __shfl_xor(dd, off, 64);
      nn += __shfl_xor(nn, off, 64);
    }
    if (lane == 0) {
      const float dtv = (float)(ct - atimes[j]);
      const float mult = powf(DECAY_RATE, dtv) * importance[j] * log1pf((float)acnts[j]);
      sc[c] = dd / (qdn * fmaxf(sqrtf(nn), DECAY_EPS)) * mult;
      sidx[c] = j;
    }
  }
  __syncthreads();

  __shared__ float w8s[8];
  __shared__ int g8[8];
  __shared__ float confv;
  __shared__ float tls[8];
  __shared__ int tli[8];
  if (w == 0) {
    float myv = sc[lane];
    for (int r = 0; r < 8; ++r) {
      float m = myv;
      int mi = lane;
#pragma unroll
      for (int off = 32; off; off >>= 1) {
        const float ov = __shfl_xor(m, off, 64);
        const int oi = __shfl_xor(mi, off, 64);
        if (ov > m || (ov == m && oi < mi)) { m = ov; mi = oi; }
      }
      if (lane == 0) { tls[r] = m; tli[r] = mi; }
      if (lane == mi) myv = -FLT_MAX;
    }
    if (lane == 0) {
      const float mx = tls[0];
      float e[8];
      float z = 0.0f;
#pragma unroll
      for (int r = 0; r < 8; ++r) { e[r] = expf(tls[r] - mx); z += e[r]; }
      const float invz = 1.0f / z;
#pragma unroll
      for (int r = 0; r < 8; ++r) { w8s[r] = e[r] * invz; g8[r] = sidx[tli[r]]; }
      confv = w8s[0];
    }
  }
  __syncthreads();

  float2 acc = make_float2(0.0f, 0.0f);
#pragma unroll
  for (int k = 0; k < 8; ++k) {
    const float wk = w8s[k];
    const float2 v = *reinterpret_cast<const float2*>(values + (size_t)g8[k] * D + 2 * t);
    acc.x = fmaf(wk, v.x, acc.x);
    acc.y = fmaf(wk, v.y, acc.y);
  }
  *reinterpret_cast<float2*>(outc + (size_t)b * D + 2 * t) = acc;
  if (t == 0) conf[b] = confv;
}

}  // namespace

extern "C" void kernel_launch(void* const* d_in, const int* in_sizes, int n_in,
                              void* d_out, int out_size, void* d_ws, size_t ws_size,
                              hipStream_t stream) {
  const float* query = (const float*)d_in[0];
  const float* keys = (const float*)d_in[1];
  const float* values = (const float*)d_in[2];
  const float* importance = (const float*)d_in[3];
  const int* atimes = (const int*)d_in[4];
  const int* acnts = (const int*)d_in[5];
  const int* ctime = (const int*)d_in[6];

  float* out = (float*)d_out;  // combined [B*D] then confidence [B]
  ushort* qnf = (ushort*)d_ws;                 // 512 KB
  ushort* scores = qnf + (size_t)B * D;        // 32 MB bf16
  int* cand = (int*)(scores + (size_t)B * M);  // 64 KB

  prep_q_kernel<<<B, 256, 0, stream>>>(query, qnf);
  score_gemm_kernel<<<M / BN, 256, 0, stream>>>(qnf, keys, importance, atimes,
                                                acnts, ctime, scores);
  dim3 gA(CHUNKS, B);
  topk_partial_kernel<<<gA, 256, 0, stream>>>(scores, cand);
  rescore_kernel<<<B, 512, 0, stream>>>(cand, query, keys, values, importance,
                                        atimes, acnts, ctime, out, out + (size_t)B * D);
}